// Round 1
// baseline (7224.763 us; speedup 1.0000x reference)
//
#include <hip/hip_runtime.h>

// LinearRNN: packed-sequence linear recurrence h' = W_hh h + W_ih x + b.
// Strategy: chunk the T=2048 scan into 128 chunks of 16 (activity boundaries
// align exactly with chunk boundaries since lengths = 2048-16i).
//   h_end(chunk c) = P16 h_start + v_c,  P_k = W_hh^k
//   v_c(b) = sum_j Q_j x_{16c+j}(b) + biasv,  Q_j = P_{15-j} W_ih,
//   biasv = (sum_{k=0..15} P_k)(b_ih + b_hh)
// All fp32 this round (correctness baseline); GEMMs are simple 64x64x16 tiles.

#define DH   1024
#define DIN  512
#define TT   2048
#define BB   64
#define NCHUNK 128
#define CSZ  16
#define NPAIR 6176   // sum_c min(64,128-c)

// ---------------- setup: offsets / chunk tables (handles i32 or i64 ints) ---
__global__ void setup_kernel(const int* __restrict__ bsz32,
                             int* __restrict__ offsets, int* __restrict__ pstart,
                             int* __restrict__ nb, int* __restrict__ srcrow,
                             int* __restrict__ flag)
{
    __shared__ int sbs[TT];
    __shared__ int soff[TT];
    __shared__ int snb[NCHUNK];
    __shared__ int sps[NCHUNK];
    __shared__ int sh_shift;
    if (threadIdx.x == 0) {
        // batch_sizes[1] is 64 (nonzero) as int32; if stored int64 the second
        // 32-bit word is the high half of value 64 -> 0.
        sh_shift = (bsz32[1] == 0) ? 1 : 0;
        flag[0] = sh_shift;
    }
    __syncthreads();
    int shf = sh_shift;
    for (int t = threadIdx.x; t < TT; t += blockDim.x) sbs[t] = bsz32[t << shf];
    __syncthreads();
    if (threadIdx.x == 0) {
        int run = 0;
        for (int t = 0; t < TT; ++t) { soff[t] = run; run += sbs[t]; }
        int pr = 0;
        for (int c = 0; c < NCHUNK; ++c) { snb[c] = sbs[c*CSZ]; sps[c] = pr; pr += snb[c]; }
    }
    __syncthreads();
    for (int t = threadIdx.x; t < TT; t += blockDim.x) offsets[t] = soff[t];
    for (int c = threadIdx.x; c < NCHUNK; c += blockDim.x) { nb[c] = snb[c]; pstart[c] = sps[c]; }
    if (threadIdx.x == 0) pstart[NCHUNK] = sps[NCHUNK-1] + snb[NCHUNK-1];
    for (int c = 0; c < NCHUNK; ++c) {
        int n = snb[c], ps = sps[c];
        for (int b = threadIdx.x; b < n; b += blockDim.x) {
            #pragma unroll
            for (int j = 0; j < CSZ; ++j)
                srcrow[(ps + b)*CSZ + j] = soff[c*CSZ + j] + b;
        }
    }
}

// ---------------- init: P0 = I, P1 = W_hh, H = 0 ----------------------------
__global__ void init_kernel(const float* __restrict__ W_hh,
                            float* __restrict__ P, float* __restrict__ H)
{
    long long i = (long long)blockIdx.x*blockDim.x + threadIdx.x;
    if (i < (long long)DH*DH) {
        int r = (int)(i / DH), cc = (int)(i % DH);
        P[i] = (r == cc) ? 1.0f : 0.0f;
        P[(long long)DH*DH + i] = W_hh[i];
    }
    if (i < 2*BB*DH) H[i] = 0.0f;
}

// ---------------- generic batched NN GEMM: C = A(M,K) * B(K,N) --------------
// row-major, lda=K ldb=N ldc=N, dims multiples of 64/16. 64x64x16 tile.
__global__ __launch_bounds__(256)
void gemm_nn_batched(const float* __restrict__ Abase, long long Astr,
                     const float* __restrict__ Bbase, long long Bstr,
                     float* __restrict__ Cbase, long long Cstr,
                     int M, int N, int K)
{
    long long z = blockIdx.z;
    const float* A = Abase + Astr*z;
    const float* B = Bbase + Bstr*z;
    float* C = Cbase + Cstr*z;
    __shared__ float As[16][68];   // [k][m], pad 68 keeps float4 align + 2-way banks
    __shared__ float Bs[16][68];   // [k][n]
    int tid = threadIdx.x;
    int row0 = blockIdx.x * 64;
    int col0 = blockIdx.y * 64;
    int tx = tid & 15, ty = tid >> 4;
    int am = tid >> 2, akq = tid & 3;     // A-tile load coords (64 rows x 4 float4)
    int bk = tid >> 4, bnq = tid & 15;    // B-tile load coords (16 k x 16 float4)
    float acc[4][4] = {};
    for (int kt = 0; kt < K; kt += 16) {
        float4 av = *(const float4*)(A + (long long)(row0+am)*K + kt + akq*4);
        float4 bv = *(const float4*)(B + (long long)(kt+bk)*N + col0 + bnq*4);
        As[akq*4+0][am]=av.x; As[akq*4+1][am]=av.y; As[akq*4+2][am]=av.z; As[akq*4+3][am]=av.w;
        *(float4*)&Bs[bk][bnq*4] = bv;
        __syncthreads();
        #pragma unroll
        for (int k = 0; k < 16; ++k) {
            float4 a4 = *(const float4*)&As[k][ty*4];
            float4 b4 = *(const float4*)&Bs[k][tx*4];
            float a[4] = {a4.x,a4.y,a4.z,a4.w};
            float b[4] = {b4.x,b4.y,b4.z,b4.w};
            #pragma unroll
            for (int i = 0; i < 4; ++i)
                #pragma unroll
                for (int j = 0; j < 4; ++j)
                    acc[i][j] += a[i]*b[j];
        }
        __syncthreads();
    }
    #pragma unroll
    for (int i = 0; i < 4; ++i) {
        float4 cv = make_float4(acc[i][0],acc[i][1],acc[i][2],acc[i][3]);
        *(float4*)(C + (long long)(row0+ty*4+i)*N + col0 + tx*4) = cv;
    }
}

// ---------------- biasv[n] = sum_{k=0..15} (P_k (b_ih+b_hh))[n] -------------
__global__ void biasv_kernel(const float* __restrict__ P,
                             const float* __restrict__ b_ih,
                             const float* __restrict__ b_hh,
                             float* __restrict__ biasv)
{
    int n = blockIdx.x;
    float s = 0.f;
    for (int m = threadIdx.x; m < DH; m += 256) {
        float bb = b_ih[m] + b_hh[m];
        float ps = 0.f;
        #pragma unroll
        for (int k = 0; k < 16; ++k) ps += P[(long long)k*DH*DH + (long long)n*DH + m];
        s += ps * bb;
    }
    __shared__ float red[256];
    red[threadIdx.x] = s; __syncthreads();
    for (int w = 128; w > 0; w >>= 1) {
        if (threadIdx.x < w) red[threadIdx.x] += red[threadIdx.x + w];
        __syncthreads();
    }
    if (threadIdx.x == 0) biasv[n] = red[0];
}

// ---------------- V[p,n] = biasv[n] + sum_j data[srcrow[p][j]] . Q_j[n] -----
// M=NPAIR (edge-guarded), N=1024, Keff = 16*512 (NT with gathered A rows)
__global__ __launch_bounds__(256)
void v_kernel(const float* __restrict__ data, const float* __restrict__ Q,
              const float* __restrict__ biasv, const int* __restrict__ srcrow,
              float* __restrict__ V)
{
    __shared__ int   s_src[64][16];
    __shared__ float As[16][68];
    __shared__ float Bs[16][68];
    int tid = threadIdx.x;
    int p0   = blockIdx.x * 64;
    int col0 = blockIdx.y * 64;
    #pragma unroll
    for (int l = 0; l < 4; ++l) {
        int idx = tid + l*256;
        int m = idx >> 4, j = idx & 15;
        int p = p0 + m; if (p > NPAIR-1) p = NPAIR-1;   // clamp: garbage rows never stored
        s_src[m][j] = srcrow[p*16 + j];
    }
    __syncthreads();
    int tx = tid & 15, ty = tid >> 4;
    int am = tid >> 2, akq = tid & 3;
    float acc[4][4] = {};
    for (int kt = 0; kt < CSZ*DIN; kt += 16) {
        int j = kt >> 9, k0 = kt & 511;
        int src = s_src[am][j];
        float4 av = *(const float4*)(data + (long long)src*DIN + k0 + akq*4);
        float4 bv = *(const float4*)(Q + ((long long)j*DH + col0 + am)*DIN + k0 + akq*4);
        As[akq*4+0][am]=av.x; As[akq*4+1][am]=av.y; As[akq*4+2][am]=av.z; As[akq*4+3][am]=av.w;
        Bs[akq*4+0][am]=bv.x; Bs[akq*4+1][am]=bv.y; Bs[akq*4+2][am]=bv.z; Bs[akq*4+3][am]=bv.w;
        __syncthreads();
        #pragma unroll
        for (int k = 0; k < 16; ++k) {
            float4 a4 = *(const float4*)&As[k][ty*4];
            float4 b4 = *(const float4*)&Bs[k][tx*4];
            float a[4] = {a4.x,a4.y,a4.z,a4.w};
            float b[4] = {b4.x,b4.y,b4.z,b4.w};
            #pragma unroll
            for (int i = 0; i < 4; ++i)
                #pragma unroll
                for (int jj = 0; jj < 4; ++jj)
                    acc[i][jj] += a[i]*b[jj];
        }
        __syncthreads();
    }
    #pragma unroll
    for (int i = 0; i < 4; ++i) {
        int p = p0 + ty*4 + i;
        if (p < NPAIR) {
            float4 cv;
            cv.x = acc[i][0] + biasv[col0+tx*4+0];
            cv.y = acc[i][1] + biasv[col0+tx*4+1];
            cv.z = acc[i][2] + biasv[col0+tx*4+2];
            cv.w = acc[i][3] + biasv[col0+tx*4+3];
            *(float4*)(V + (long long)p*DH + col0 + tx*4) = cv;
        }
    }
}

// ---------------- one scan step: Hout = (active ? Hin*P16^T + V : Hin) ------
// grid (4,16): 16 rows x 64 cols per block, full K=1024 per block.
__global__ __launch_bounds__(256)
void step_kernel(const float* __restrict__ Hin, const float* __restrict__ P16,
                 const float* __restrict__ V, const int* __restrict__ nb,
                 const int* __restrict__ pstart, float* __restrict__ Hout, int c)
{
    __shared__ float As[16][17];   // [k][local row]
    __shared__ float Bs[16][68];   // [k][n]
    int tid = threadIdx.x;
    int tx = tid & 15, ty = tid >> 4;
    int r0 = blockIdx.x * 16;
    int col0 = blockIdx.y * 64;
    int nbc = nb[c], ps = pstart[c];
    int bn = tid >> 2, bkq = tid & 3;
    float acc[4] = {0.f,0.f,0.f,0.f};
    for (int kt = 0; kt < DH; kt += 16) {
        As[tx][ty] = Hin[(long long)(r0+ty)*DH + kt + tx];
        float4 bv = *(const float4*)(P16 + (long long)(col0+bn)*DH + kt + bkq*4);
        Bs[bkq*4+0][bn]=bv.x; Bs[bkq*4+1][bn]=bv.y; Bs[bkq*4+2][bn]=bv.z; Bs[bkq*4+3][bn]=bv.w;
        __syncthreads();
        #pragma unroll
        for (int k = 0; k < 16; ++k) {
            float a = As[k][ty];
            float4 b4 = *(const float4*)&Bs[k][tx*4];
            acc[0] += a*b4.x; acc[1] += a*b4.y; acc[2] += a*b4.z; acc[3] += a*b4.w;
        }
        __syncthreads();
    }
    int row = r0 + ty;
    float4 ov;
    if (row < nbc) {
        const float* vr = V + (long long)(ps+row)*DH + col0 + tx*4;
        ov.x = acc[0]+vr[0]; ov.y = acc[1]+vr[1]; ov.z = acc[2]+vr[2]; ov.w = acc[3]+vr[3];
    } else {
        ov = *(const float4*)(Hin + (long long)row*DH + col0 + tx*4);
    }
    *(float4*)(Hout + (long long)row*DH + col0 + tx*4) = ov;
}

// ---------------- output gather -------------------------------------------
__global__ void out_kernel(const float* __restrict__ H, const int* __restrict__ unsort32,
                           const int* __restrict__ flag, float* __restrict__ out)
{
    int i = blockIdx.x*blockDim.x + threadIdx.x;
    int q = i >> 10, n = i & (DH-1);
    int shf = flag[0];
    out[i] = H[(long long)unsort32[q << shf]*DH + n];
}

extern "C" void kernel_launch(void* const* d_in, const int* in_sizes, int n_in,
                              void* d_out, int out_size, void* d_ws, size_t ws_size,
                              hipStream_t stream)
{
    const float* data   = (const float*)d_in[0];
    const int*   bsz    = (const int*)d_in[1];
    const int*   unsort = (const int*)d_in[2];
    const float* W_ih   = (const float*)d_in[3];
    const float* b_ih   = (const float*)d_in[4];
    const float* W_hh   = (const float*)d_in[5];
    const float* b_hh   = (const float*)d_in[6];
    float* out = (float*)d_out;

    // ---- workspace layout (~131 MB) ----
    char* ws = (char*)d_ws;
    size_t off = 0;
    auto alloc = [&](size_t bytes) -> void* {
        void* p = ws + off;
        off = (off + bytes + 255) & ~(size_t)255;
        return p;
    };
    int*   offsets = (int*)  alloc((size_t)TT*4);
    int*   pstart  = (int*)  alloc((NCHUNK+1)*4);
    int*   nb      = (int*)  alloc(NCHUNK*4);
    int*   srcrow  = (int*)  alloc((size_t)NPAIR*CSZ*4);
    int*   flag    = (int*)  alloc(4);
    float* P       = (float*)alloc(17ull*DH*DH*4);       // P_0..P_16
    float* Q       = (float*)alloc(16ull*DH*DIN*4);      // Q_j = P_{15-j} W_ih
    float* biasv   = (float*)alloc((size_t)DH*4);
    float* V       = (float*)alloc((size_t)NPAIR*DH*4);
    float* H       = (float*)alloc(2ull*BB*DH*4);        // ping-pong
    (void)ws_size; (void)n_in; (void)in_sizes; (void)out_size;

    const size_t SZ = (size_t)DH*DH;

    setup_kernel<<<1,256,0,stream>>>(bsz, offsets, pstart, nb, srcrow, flag);
    init_kernel<<<(DH*DH+255)/256,256,0,stream>>>(W_hh, P, H);

    // powers by doubling: P_{m+j} = P_m * P_j, j=1..m, for m=1,2,4,8 -> P_2..P_16
    for (int m = 1; m <= 8; m <<= 1) {
        gemm_nn_batched<<<dim3(16,16,m),256,0,stream>>>(
            P + (size_t)m*SZ, 0,
            P + SZ,           (long long)SZ,
            P + (size_t)(m+1)*SZ, (long long)SZ,
            DH, DH, DH);
    }
    // Q_j = P_{15-j} * W_ih  (batch over j, A stride -SZ from P_15)
    gemm_nn_batched<<<dim3(16,8,16),256,0,stream>>>(
        P + 15ull*SZ, -(long long)SZ,
        W_ih, 0,
        Q, (long long)DH*DIN,
        DH, DIN, DH);

    biasv_kernel<<<DH,256,0,stream>>>(P, b_ih, b_hh, biasv);

    v_kernel<<<dim3((NPAIR+63)/64, DH/64),256,0,stream>>>(data, Q, biasv, srcrow, V);

    for (int c = 0; c < NCHUNK; ++c) {
        step_kernel<<<dim3(4,16),256,0,stream>>>(
            H + (size_t)(c&1)*BB*DH,
            P + 16ull*SZ,
            V, nb, pstart,
            H + (size_t)((c+1)&1)*BB*DH, c);
    }
    // final state lands in H[0] after 128 steps
    out_kernel<<<out_size/256,256,0,stream>>>(H, unsort, flag, out);
}

// Round 2
// 5615.993 us; speedup vs baseline: 1.2865x; 1.2865x over previous
//
#include <hip/hip_runtime.h>

// LinearRNN: packed-sequence linear recurrence h' = W_hh h + W_ih x + b.
// Two-level chunking (exact):
//   Level 1: chunks of 16 steps. v_c(b) = sum_j Q_j x + biasv, Q_j = P_{15-j} W_ih.
//   Level 2: groups of 16 chunks. S_j = P16^j.
//     w_g(b) = sum_j S_{15-j} v_{16g+j}(b)          (parallel gather-GEMM)
//     scan:  h <- S_16 h + w_g, g=0..6 (7 sequential steps, snapshots kept)
//     finalize (all rows): h_b = sum_{k<a_b} S_k v_{127-b-k}(b) + S_{a_b} Hsnap[g_b][b]
//       with g_b=(127-b)>>4, a_b=16-(b&15)          (one gather-GEMM, M=64)
// All fp32 this round. S_j aliased into P slots after Q/biasv consume P_0..15:
//   slot(S_j): j==0 -> 15 (identity), j==1 -> 16 (=P_16), else j-2.

#define DH   1024
#define DIN  512
#define TT   2048
#define BB   64
#define NCHUNK 128
#define CSZ  16
#define NPAIR 6176         // sum_c nb[c]
#define NWP  355           // sum_{g=0..6} min(64,113-16g)
#define ZROW (NPAIR+512)   // zero row in Vbig
#define SZLL 1048576ll     // DH*DH

__device__ __forceinline__ int sslot_dev(int j) {
    return j == 0 ? 15 : (j == 1 ? 16 : j - 2);
}

// ---------------- setup: offsets / chunk / gather tables --------------------
__global__ void setup_kernel(const int* __restrict__ bsz32,
                             int* __restrict__ pstart,
                             int* __restrict__ nb, int* __restrict__ srcrow,
                             int* __restrict__ wsrc, int* __restrict__ fix_src,
                             int* __restrict__ bidx_w, int* __restrict__ bidx_fix,
                             int* __restrict__ flag)
{
    __shared__ int sbs[TT];
    __shared__ int soff[TT];
    __shared__ int snb[NCHUNK];
    __shared__ int sps[NCHUNK];
    __shared__ int s_nf[7], s_wps[7];
    __shared__ int sh_shift;
    int tid = threadIdx.x;
    if (tid == 0) {
        // batch_sizes[1]==64 nonzero as int32; if int64, second word is 0.
        sh_shift = (bsz32[1] == 0) ? 1 : 0;
        flag[0] = sh_shift;
    }
    __syncthreads();
    int shf = sh_shift;
    for (int t = tid; t < TT; t += 256) sbs[t] = bsz32[t << shf];
    __syncthreads();
    if (tid == 0) {
        int run = 0;
        for (int t = 0; t < TT; ++t) { soff[t] = run; run += sbs[t]; }
        int pr = 0;
        for (int c = 0; c < NCHUNK; ++c) { snb[c] = sbs[c*CSZ]; sps[c] = pr; pr += snb[c]; }
        int wp = 0;
        for (int g = 0; g < 7; ++g) {
            int nf = 113 - 16*g; if (nf > 64) nf = 64;
            s_nf[g] = nf; s_wps[g] = wp; wp += nf;
        }
    }
    __syncthreads();
    for (int c = tid; c < NCHUNK; c += 256) { nb[c] = snb[c]; pstart[c] = sps[c]; }
    if (tid == 0) pstart[NCHUNK] = sps[NCHUNK-1] + snb[NCHUNK-1];
    // srcrow for v_kernel
    for (int c = 0; c < NCHUNK; ++c) {
        int n = snb[c], ps = sps[c];
        for (int b = tid; b < n; b += 256) {
            #pragma unroll
            for (int j = 0; j < CSZ; ++j)
                srcrow[(ps + b)*CSZ + j] = soff[c*CSZ + j] + b;
        }
    }
    // wsrc for w gather-GEMM: row wp=(g,b), block j -> V row pstart[16g+j]+b
    for (int g = 0; g < 7; ++g) {
        for (int b = tid; b < s_nf[g]; b += 256) {
            int wp = s_wps[g] + b;
            #pragma unroll
            for (int j = 0; j < CSZ; ++j)
                wsrc[wp*CSZ + j] = sps[16*g + j] + b;
        }
    }
    // fix_src: row b, 17 blocks
    if (tid < 64) {
        int b = tid;
        int gb = (127 - b) >> 4;
        int ab = 16 - (b & 15);
        for (int k = 0; k <= 16; ++k) {
            int r;
            if (k < ab)       r = sps[127 - b - k] + b;
            else if (k == ab) r = NPAIR + 64*gb + b;
            else              r = ZROW;
            fix_src[b*17 + k] = r;
        }
    }
    if (tid < 16) bidx_w[tid]  = sslot_dev(15 - tid);
    if (tid < 17) bidx_fix[tid] = sslot_dev(tid);
}

// ---------------- init: P0 = I, P1 = W_hh, Vbig snapshot/zero rows ----------
__global__ void init_kernel(const float* __restrict__ W_hh,
                            float* __restrict__ P, float* __restrict__ Vbig)
{
    long long i = (long long)blockIdx.x*blockDim.x + threadIdx.x;
    if (i < SZLL) {
        int r = (int)(i >> 10), cc = (int)(i & 1023);
        P[i] = (r == cc) ? 1.0f : 0.0f;
        P[SZLL + i] = W_hh[i];
    }
    if (i < 576ll*DH) Vbig[(long long)NPAIR*DH + i] = 0.0f;  // H_0 + pad + ZROW
}

// ---------------- identity into P slot 15 (after Q/biasv read P_15) ---------
__global__ void initS_kernel(float* __restrict__ P)
{
    long long i = (long long)blockIdx.x*blockDim.x + threadIdx.x;
    if (i < SZLL) {
        int r = (int)(i >> 10), cc = (int)(i & 1023);
        P[15*SZLL + i] = (r == cc) ? 1.0f : 0.0f;
    }
}

// ---------------- generic batched NN GEMM: C = A(M,K) * B(K,N) --------------
__global__ __launch_bounds__(256)
void gemm_nn_batched(const float* __restrict__ Abase, long long Astr,
                     const float* __restrict__ Bbase, long long Bstr,
                     float* __restrict__ Cbase, long long Cstr,
                     int M, int N, int K)
{
    long long z = blockIdx.z;
    const float* A = Abase + Astr*z;
    const float* B = Bbase + Bstr*z;
    float* C = Cbase + Cstr*z;
    __shared__ float As[16][68];
    __shared__ float Bs[16][68];
    int tid = threadIdx.x;
    int row0 = blockIdx.x * 64;
    int col0 = blockIdx.y * 64;
    int tx = tid & 15, ty = tid >> 4;
    int am = tid >> 2, akq = tid & 3;
    int bk = tid >> 4, bnq = tid & 15;
    float acc[4][4] = {};
    for (int kt = 0; kt < K; kt += 16) {
        float4 av = *(const float4*)(A + (long long)(row0+am)*K + kt + akq*4);
        float4 bv = *(const float4*)(B + (long long)(kt+bk)*N + col0 + bnq*4);
        As[akq*4+0][am]=av.x; As[akq*4+1][am]=av.y; As[akq*4+2][am]=av.z; As[akq*4+3][am]=av.w;
        *(float4*)&Bs[bk][bnq*4] = bv;
        __syncthreads();
        #pragma unroll
        for (int k = 0; k < 16; ++k) {
            float4 a4 = *(const float4*)&As[k][ty*4];
            float4 b4 = *(const float4*)&Bs[k][tx*4];
            float a[4] = {a4.x,a4.y,a4.z,a4.w};
            float b[4] = {b4.x,b4.y,b4.z,b4.w};
            #pragma unroll
            for (int i = 0; i < 4; ++i)
                #pragma unroll
                for (int j = 0; j < 4; ++j)
                    acc[i][j] += a[i]*b[j];
        }
        __syncthreads();
    }
    #pragma unroll
    for (int i = 0; i < 4; ++i) {
        float4 cv = make_float4(acc[i][0],acc[i][1],acc[i][2],acc[i][3]);
        *(float4*)(C + (long long)(row0+ty*4+i)*N + col0 + tx*4) = cv;
    }
}

// ---------------- biasv[n] = sum_{k=0..15} (P_k (b_ih+b_hh))[n] -------------
__global__ void biasv_kernel(const float* __restrict__ P,
                             const float* __restrict__ b_ih,
                             const float* __restrict__ b_hh,
                             float* __restrict__ biasv)
{
    int n = blockIdx.x;
    float s = 0.f;
    for (int m = threadIdx.x; m < DH; m += 256) {
        float bb = b_ih[m] + b_hh[m];
        float ps = 0.f;
        #pragma unroll
        for (int k = 0; k < 16; ++k) ps += P[(long long)k*SZLL + (long long)n*DH + m];
        s += ps * bb;
    }
    __shared__ float red[256];
    red[threadIdx.x] = s; __syncthreads();
    for (int w = 128; w > 0; w >>= 1) {
        if (threadIdx.x < w) red[threadIdx.x] += red[threadIdx.x + w];
        __syncthreads();
    }
    if (threadIdx.x == 0) biasv[n] = red[0];
}

// ---------------- V[p,n] = biasv[n] + sum_j data[srcrow[p][j]] . Q_j[n] -----
__global__ __launch_bounds__(256)
void v_kernel(const float* __restrict__ data, const float* __restrict__ Q,
              const float* __restrict__ biasv, const int* __restrict__ srcrow,
              float* __restrict__ V)
{
    __shared__ int   s_src[64][16];
    __shared__ float As[16][68];
    __shared__ float Bs[16][68];
    int tid = threadIdx.x;
    int p0   = blockIdx.x * 64;
    int col0 = blockIdx.y * 64;
    #pragma unroll
    for (int l = 0; l < 4; ++l) {
        int idx = tid + l*256;
        int m = idx >> 4, j = idx & 15;
        int p = p0 + m; if (p > NPAIR-1) p = NPAIR-1;
        s_src[m][j] = srcrow[p*16 + j];
    }
    __syncthreads();
    int tx = tid & 15, ty = tid >> 4;
    int am = tid >> 2, akq = tid & 3;
    float acc[4][4] = {};
    for (int kt = 0; kt < CSZ*DIN; kt += 16) {
        int j = kt >> 9, k0 = kt & 511;
        int src = s_src[am][j];
        float4 av = *(const float4*)(data + (long long)src*DIN + k0 + akq*4);
        float4 bv = *(const float4*)(Q + ((long long)j*DH + col0 + am)*DIN + k0 + akq*4);
        As[akq*4+0][am]=av.x; As[akq*4+1][am]=av.y; As[akq*4+2][am]=av.z; As[akq*4+3][am]=av.w;
        Bs[akq*4+0][am]=bv.x; Bs[akq*4+1][am]=bv.y; Bs[akq*4+2][am]=bv.z; Bs[akq*4+3][am]=bv.w;
        __syncthreads();
        #pragma unroll
        for (int k = 0; k < 16; ++k) {
            float4 a4 = *(const float4*)&As[k][ty*4];
            float4 b4 = *(const float4*)&Bs[k][tx*4];
            float a[4] = {a4.x,a4.y,a4.z,a4.w};
            float b[4] = {b4.x,b4.y,b4.z,b4.w};
            #pragma unroll
            for (int i = 0; i < 4; ++i)
                #pragma unroll
                for (int jj = 0; jj < 4; ++jj)
                    acc[i][jj] += a[i]*b[jj];
        }
        __syncthreads();
    }
    #pragma unroll
    for (int i = 0; i < 4; ++i) {
        int p = p0 + ty*4 + i;
        if (p < NPAIR) {
            float4 cv;
            cv.x = acc[i][0] + biasv[col0+tx*4+0];
            cv.y = acc[i][1] + biasv[col0+tx*4+1];
            cv.z = acc[i][2] + biasv[col0+tx*4+2];
            cv.w = acc[i][3] + biasv[col0+tx*4+3];
            *(float4*)(V + (long long)p*DH + col0 + tx*4) = cv;
        }
    }
}

// ---------------- gather-GEMM over stacked S matrices -----------------------
// C[p,n] = sum_{j<KB} Arows[src[p][j]] . Sbase[bidx[j]][n,:]   (K-block = 1024)
__global__ __launch_bounds__(256)
void gg_kernel(const float* __restrict__ Arows, const float* __restrict__ Sbase,
               const int* __restrict__ src, const int* __restrict__ bidx,
               float* __restrict__ C, int M, int KB)
{
    __shared__ int   s_src[64][17];
    __shared__ int   s_b[17];
    __shared__ float As[16][68];
    __shared__ float Bs[16][68];
    int tid = threadIdx.x;
    int p0   = blockIdx.x * 64;
    int col0 = blockIdx.y * 64;
    if (tid < KB) s_b[tid] = bidx[tid];
    for (int idx = tid; idx < 64*KB; idx += 256) {
        int m = idx / KB, j = idx - m*KB;
        int p = p0 + m; if (p > M-1) p = M-1;
        s_src[m][j] = src[p*KB + j];
    }
    __syncthreads();
    int tx = tid & 15, ty = tid >> 4;
    int am = tid >> 2, akq = tid & 3;
    float acc[4][4] = {};
    int K = KB << 10;
    for (int kt = 0; kt < K; kt += 16) {
        int j = kt >> 10, k0 = kt & 1023;
        int src_r = s_src[am][j];
        float4 av = *(const float4*)(Arows + (long long)src_r*DH + k0 + akq*4);
        float4 bv = *(const float4*)(Sbase + (long long)s_b[j]*SZLL
                                     + (long long)(col0+am)*DH + k0 + akq*4);
        As[akq*4+0][am]=av.x; As[akq*4+1][am]=av.y; As[akq*4+2][am]=av.z; As[akq*4+3][am]=av.w;
        Bs[akq*4+0][am]=bv.x; Bs[akq*4+1][am]=bv.y; Bs[akq*4+2][am]=bv.z; Bs[akq*4+3][am]=bv.w;
        __syncthreads();
        #pragma unroll
        for (int k = 0; k < 16; ++k) {
            float4 a4 = *(const float4*)&As[k][ty*4];
            float4 b4 = *(const float4*)&Bs[k][tx*4];
            float a[4] = {a4.x,a4.y,a4.z,a4.w};
            float b[4] = {b4.x,b4.y,b4.z,b4.w};
            #pragma unroll
            for (int i = 0; i < 4; ++i)
                #pragma unroll
                for (int jj = 0; jj < 4; ++jj)
                    acc[i][jj] += a[i]*b[jj];
        }
        __syncthreads();
    }
    #pragma unroll
    for (int i = 0; i < 4; ++i) {
        int p = p0 + ty*4 + i;
        if (p < M) {
            float4 cv = make_float4(acc[i][0],acc[i][1],acc[i][2],acc[i][3]);
            *(float4*)(C + (long long)p*DH + col0 + tx*4) = cv;
        }
    }
}

// ---------------- level-2 scan step: Hout = (b<nfull ? S16 Hin + W : Hin) ---
__global__ __launch_bounds__(256)
void step2_kernel(const float* __restrict__ Hin, const float* __restrict__ S16,
                  const float* __restrict__ Wg, float* __restrict__ Hout, int nfull)
{
    __shared__ float As[16][17];
    __shared__ float Bs[16][68];
    int tid = threadIdx.x;
    int tx = tid & 15, ty = tid >> 4;
    int r0 = blockIdx.x * 16;
    int col0 = blockIdx.y * 64;
    int bn = tid >> 2, bkq = tid & 3;
    float acc[4] = {0.f,0.f,0.f,0.f};
    for (int kt = 0; kt < DH; kt += 16) {
        As[tx][ty] = Hin[(long long)(r0+ty)*DH + kt + tx];
        float4 bv = *(const float4*)(S16 + (long long)(col0+bn)*DH + kt + bkq*4);
        Bs[bkq*4+0][bn]=bv.x; Bs[bkq*4+1][bn]=bv.y; Bs[bkq*4+2][bn]=bv.z; Bs[bkq*4+3][bn]=bv.w;
        __syncthreads();
        #pragma unroll
        for (int k = 0; k < 16; ++k) {
            float a = As[k][ty];
            float4 b4 = *(const float4*)&Bs[k][tx*4];
            acc[0] += a*b4.x; acc[1] += a*b4.y; acc[2] += a*b4.z; acc[3] += a*b4.w;
        }
        __syncthreads();
    }
    int row = r0 + ty;
    float4 ov;
    if (row < nfull) {
        const float* wr = Wg + (long long)row*DH + col0 + tx*4;
        ov.x = acc[0]+wr[0]; ov.y = acc[1]+wr[1]; ov.z = acc[2]+wr[2]; ov.w = acc[3]+wr[3];
    } else {
        ov = *(const float4*)(Hin + (long long)row*DH + col0 + tx*4);
    }
    *(float4*)(Hout + (long long)row*DH + col0 + tx*4) = ov;
}

// ---------------- output gather -------------------------------------------
__global__ void out_kernel(const float* __restrict__ H, const int* __restrict__ unsort32,
                           const int* __restrict__ flag, float* __restrict__ out)
{
    int i = blockIdx.x*blockDim.x + threadIdx.x;
    int q = i >> 10, n = i & (DH-1);
    int shf = flag[0];
    out[i] = H[(long long)unsort32[q << shf]*DH + n];
}

extern "C" void kernel_launch(void* const* d_in, const int* in_sizes, int n_in,
                              void* d_out, int out_size, void* d_ws, size_t ws_size,
                              hipStream_t stream)
{
    const float* data   = (const float*)d_in[0];
    const int*   bsz    = (const int*)d_in[1];
    const int*   unsort = (const int*)d_in[2];
    const float* W_ih   = (const float*)d_in[3];
    const float* b_ih   = (const float*)d_in[4];
    const float* W_hh   = (const float*)d_in[5];
    const float* b_hh   = (const float*)d_in[6];
    float* out = (float*)d_out;

    char* ws = (char*)d_ws;
    size_t off = 0;
    auto alloc = [&](size_t bytes) -> void* {
        void* p = ws + off;
        off = (off + bytes + 255) & ~(size_t)255;
        return p;
    };
    int*   pstart  = (int*)  alloc((NCHUNK+1)*4);
    int*   nbt     = (int*)  alloc(NCHUNK*4);
    int*   srcrow  = (int*)  alloc((size_t)NPAIR*CSZ*4);
    int*   wsrc    = (int*)  alloc((size_t)384*CSZ*4);
    int*   fix_src = (int*)  alloc((size_t)64*17*4);
    int*   bidx_w  = (int*)  alloc(16*4);
    int*   bidx_fix= (int*)  alloc(17*4);
    int*   flag    = (int*)  alloc(4);
    float* P       = (float*)alloc(17ull*DH*DH*4);   // P_0..P_16, later S slots
    float* Q       = (float*)alloc(16ull*DH*DIN*4);
    float* biasv   = (float*)alloc((size_t)DH*4);
    float* Vbig    = (float*)alloc((size_t)(NPAIR+576)*DH*4); // V | Hsnap 0..7 | ZROW
    float* W       = (float*)alloc((size_t)384*DH*4);
    float* Hfinal  = (float*)alloc((size_t)BB*DH*4);
    (void)ws_size; (void)n_in; (void)in_sizes; (void)nbt;

    const size_t SZ = (size_t)DH*DH;
    auto sslot = [](int j){ return j == 0 ? 15 : (j == 1 ? 16 : j - 2); };

    setup_kernel<<<1,256,0,stream>>>(bsz, pstart, nbt, srcrow, wsrc, fix_src,
                                     bidx_w, bidx_fix, flag);
    init_kernel<<<(DH*DH+255)/256,256,0,stream>>>(W_hh, P, Vbig);

    // P-ladder: P_2..P_16
    for (int m = 1; m <= 8; m <<= 1) {
        gemm_nn_batched<<<dim3(16,16,m),256,0,stream>>>(
            P + (size_t)m*SZ, 0,
            P + SZ,           (long long)SZ,
            P + (size_t)(m+1)*SZ, (long long)SZ,
            DH, DH, DH);
    }
    // Q_j = P_{15-j} * W_ih
    gemm_nn_batched<<<dim3(16,8,16),256,0,stream>>>(
        P + 15ull*SZ, -(long long)SZ,
        W_ih, 0,
        Q, (long long)DH*DIN,
        DH, DIN, DH);
    biasv_kernel<<<DH,256,0,stream>>>(P, b_ih, b_hh, biasv);

    v_kernel<<<dim3((NPAIR+63)/64, DH/64),256,0,stream>>>(data, Q, biasv, srcrow, Vbig);

    // S-ladder (S_j = P16^j) aliased into P slots; P_0..P_15 consumed above.
    initS_kernel<<<(DH*DH+255)/256,256,0,stream>>>(P);        // slot 15 = I = S_0
    for (int m = 1; m <= 8; m <<= 1) {
        // j = 1: S_{m+1} = S_m * S_1  (S_1 at slot 16)
        gemm_nn_batched<<<dim3(16,16,1),256,0,stream>>>(
            P + (size_t)sslot(m)*SZ, 0,
            P + 16ull*SZ, 0,
            P + (size_t)sslot(m+1)*SZ, 0,
            DH, DH, DH);
        if (m > 1) {
            // j = 2..m: S_{m+j} = S_m * S_j  (S_2.. at slots 0.., C at slots sslot(m+2)..)
            gemm_nn_batched<<<dim3(16,16,m-1),256,0,stream>>>(
                P + (size_t)sslot(m)*SZ, 0,
                P + 0,                (long long)SZ,
                P + (size_t)sslot(m+2)*SZ, (long long)SZ,
                DH, DH, DH);
        }
    }

    // w_g for fully-active rows: M=355, KB=16
    gg_kernel<<<dim3((NWP+63)/64, DH/64),256,0,stream>>>(
        Vbig, P, wsrc, bidx_w, W, NWP, 16);

    // level-2 scan: 7 steps over group snapshots in Vbig
    int wps = 0;
    for (int g = 0; g < 7; ++g) {
        int nf = 113 - 16*g; if (nf > 64) nf = 64;
        step2_kernel<<<dim3(4,16),256,0,stream>>>(
            Vbig + (size_t)(NPAIR + 64*g)*DH,
            P + (size_t)sslot(16)*SZ,
            W + (size_t)wps*DH,
            Vbig + (size_t)(NPAIR + 64*(g+1))*DH,
            nf);
        wps += nf;
    }

    // finalize all 64 rows: KB=17 gather-GEMM
    gg_kernel<<<dim3(1, DH/64),256,0,stream>>>(
        Vbig, P, fix_src, bidx_fix, Hfinal, BB, 17);

    out_kernel<<<out_size/256,256,0,stream>>>(Hfinal, unsort, flag, out);
}

// Round 3
// 2049.274 us; speedup vs baseline: 3.5255x; 2.7405x over previous
//
#include <hip/hip_runtime.h>

// LinearRNN: packed-sequence linear recurrence h' = W_hh h + W_ih x + b.
// Two-level chunking (exact), all heavy GEMMs via one universal MFMA kernel:
//   split-bf16 (hi+lo) on-the-fly staging, 3 segments hi*hi + lo*hi + hi*lo,
//   128x128 tile, 4 waves x (64x64), v_mfma_f32_16x16x32_bf16.
// NT convention: C[r][c] = sum_k A[r][k] * Bt[c][k]  (Bt row-major N x K).
// Ladder B-operands supplied as explicit fp32 transposes (T slots).

#define DH   1024
#define DIN  512
#define TT   2048
#define BB   64
#define NCHUNK 128
#define CSZ  16
#define NPAIR 6176         // sum_c nb[c]
#define NWP  355           // sum_{g=0..6} min(64,113-16g)
#define ZROW (NPAIR+512)   // zero row in Vbig
#define SZLL 1048576ll     // DH*DH

typedef __attribute__((ext_vector_type(8))) short bf8_t;
typedef __attribute__((ext_vector_type(4))) float f4_t;

__device__ __forceinline__ unsigned short f2bf(float x) {
    unsigned u = __float_as_uint(x);
    u += 0x7fffu + ((u >> 16) & 1u);
    return (unsigned short)(u >> 16);
}
__device__ __forceinline__ float bf2f(unsigned short h) {
    return __uint_as_float((unsigned)h << 16);
}

__device__ __forceinline__ int sslot_dev(int j) {
    return j == 0 ? 15 : (j == 1 ? 16 : j - 2);
}

// ---------------- setup: chunk / gather tables ------------------------------
__global__ void setup_kernel(const int* __restrict__ bsz32,
                             int* __restrict__ pstart,
                             int* __restrict__ nb, int* __restrict__ srcrow,
                             int* __restrict__ wsrc, int* __restrict__ fix_src,
                             int* __restrict__ bidx_w, int* __restrict__ bidx_fix,
                             int* __restrict__ idt, int* __restrict__ flag)
{
    __shared__ int sbs[TT];
    __shared__ int soff[TT];
    __shared__ int snb[NCHUNK];
    __shared__ int sps[NCHUNK];
    __shared__ int s_nf[7], s_wps[7];
    __shared__ int sh_shift;
    int tid = threadIdx.x;
    if (tid == 0) {
        sh_shift = (bsz32[1] == 0) ? 1 : 0;   // int64 detection
        flag[0] = sh_shift;
    }
    __syncthreads();
    int shf = sh_shift;
    for (int t = tid; t < TT; t += 256) sbs[t] = bsz32[t << shf];
    __syncthreads();
    if (tid == 0) {
        int run = 0;
        for (int t = 0; t < TT; ++t) { soff[t] = run; run += sbs[t]; }
        int pr = 0;
        for (int c = 0; c < NCHUNK; ++c) { snb[c] = sbs[c*CSZ]; sps[c] = pr; pr += snb[c]; }
        int wp = 0;
        for (int g = 0; g < 7; ++g) {
            int nf = 113 - 16*g; if (nf > 64) nf = 64;
            s_nf[g] = nf; s_wps[g] = wp; wp += nf;
        }
    }
    __syncthreads();
    for (int c = tid; c < NCHUNK; c += 256) { nb[c] = snb[c]; pstart[c] = sps[c]; }
    if (tid == 0) pstart[NCHUNK] = sps[NCHUNK-1] + snb[NCHUNK-1];
    for (int c = 0; c < NCHUNK; ++c) {
        int n = snb[c], ps = sps[c];
        for (int b = tid; b < n; b += 256) {
            #pragma unroll
            for (int j = 0; j < CSZ; ++j)
                srcrow[(ps + b)*CSZ + j] = soff[c*CSZ + j] + b;
        }
    }
    for (int g = 0; g < 7; ++g) {
        for (int b = tid; b < s_nf[g]; b += 256) {
            int wp = s_wps[g] + b;
            #pragma unroll
            for (int j = 0; j < CSZ; ++j)
                wsrc[wp*CSZ + j] = sps[16*g + j] + b;
        }
    }
    if (tid < 64) {
        int b = tid;
        int gb = (127 - b) >> 4;
        int ab = 16 - (b & 15);
        for (int k = 0; k <= 16; ++k) {
            int r;
            if (k < ab)       r = sps[127 - b - k] + b;
            else if (k == ab) r = NPAIR + 64*gb + b;
            else              r = ZROW;
            fix_src[b*17 + k] = r;
        }
    }
    if (tid < 16) bidx_w[tid]   = sslot_dev(15 - tid);
    if (tid < 17) bidx_fix[tid] = sslot_dev(tid);
    if (tid < 17) idt[tid] = tid;
}

// ---------------- init: P0 = I, P1 = W_hh, zero Vbig tail / W / Hfinal ------
__global__ void init_kernel(const float* __restrict__ W_hh,
                            float* __restrict__ P, float* __restrict__ Vbig,
                            float* __restrict__ W, float* __restrict__ Hf)
{
    long long i = (long long)blockIdx.x*blockDim.x + threadIdx.x;
    if (i < SZLL) {
        int r = (int)(i >> 10), cc = (int)(i & 1023);
        P[i] = (r == cc) ? 1.0f : 0.0f;
        P[SZLL + i] = W_hh[i];
    }
    if (i < 576ll*DH) Vbig[(long long)NPAIR*DH + i] = 0.0f;
    if (i < 384ll*DH) W[i] = 0.0f;
    if (i < 64ll*DH)  Hf[i] = 0.0f;
}

// ---------------- identity into P slot 15 (S_0), after Q/biasv read P_15 ----
__global__ void initS_kernel(float* __restrict__ P)
{
    long long i = (long long)blockIdx.x*blockDim.x + threadIdx.x;
    if (i < SZLL) {
        int r = (int)(i >> 10), cc = (int)(i & 1023);
        P[15*SZLL + i] = (r == cc) ? 1.0f : 0.0f;
    }
}

// ---------------- generic fp32 transpose: dst[C][R] = src[R][C]^T -----------
__global__ void transpose_kernel(const float* __restrict__ src, float* __restrict__ dst,
                                 long long sstr, long long dstr, int R, int C)
{
    __shared__ float tile[32][33];
    const float* S = src + sstr*blockIdx.z;
    float* D = dst + dstr*blockIdx.z;
    int r0 = blockIdx.x*32, c0 = blockIdx.y*32;
    int tx = threadIdx.x & 31, ty = threadIdx.x >> 5;
    #pragma unroll
    for (int i = 0; i < 4; ++i)
        tile[ty + i*8][tx] = S[(long long)(r0 + ty + i*8)*C + c0 + tx];
    __syncthreads();
    #pragma unroll
    for (int i = 0; i < 4; ++i)
        D[(long long)(c0 + ty + i*8)*R + r0 + tx] = tile[tx][ty + i*8];
}

// ---------------- universal split-bf16 MFMA NT GEMM -------------------------
// C[r][c] (+)= sum_kb sum_kk A(r, kb, kk) * Bt(bidx[kb])[c][kk]
//   A: gather (src[r][kb] row in units of KBS) or dense (row len = KBtot*KBS)
//   z-dim: batch (Astr/Bzstr/Cstr) when KBz==KBtot, else split-K over kb.
// EPI: 0 = store fp32, 1 = store fp32 + bias[col], 2 = atomicAdd.
template<int EPI>
__global__ __launch_bounds__(256)
void mfma_nt(const float* __restrict__ A, long long Astr,
             const float* __restrict__ B, long long Bstr, long long Bzstr,
             float* __restrict__ C, long long Cstr, int ldc,
             const int* __restrict__ src, const int* __restrict__ bidx,
             const float* __restrict__ bias,
             int M, int KBtot, int kbs_shift, int KBz)
{
    __shared__ __align__(16) short Ah[128][40];
    __shared__ __align__(16) short Al[128][40];
    __shared__ __align__(16) short Bh[128][40];
    __shared__ __align__(16) short Bl[128][40];
    __shared__ int s_srcf[128*17];

    int tid = threadIdx.x;
    int row0 = blockIdx.x * 128;
    int col0 = blockIdx.y * 128;
    int z = blockIdx.z;
    int KBS = 1 << kbs_shift;
    int Ktot = KBtot << kbs_shift;

    bool splitK = (KBz < KBtot);
    int kb0 = splitK ? z*KBz : 0;
    int kb1 = splitK ? min(kb0 + KBz, KBtot) : KBtot;
    long long zA = splitK ? 0 : Astr*z;
    long long zB = splitK ? 0 : Bzstr*z;
    long long zC = splitK ? 0 : Cstr*z;

    if (src) {
        for (int i = tid; i < 128*KBtot; i += 256) {
            int r = i / KBtot, kb = i - r*KBtot;
            int p = row0 + r; if (p > M-1) p = M-1;
            s_srcf[i] = src[p*KBtot + kb];
        }
        __syncthreads();
    }

    int r = tid >> 1, half = tid & 1;         // staging coords
    int lane = tid & 63, wv = tid >> 6;
    int wr = (wv & 1) * 64, wc = (wv >> 1) * 64;
    int m16 = lane & 15, q = lane >> 4;

    f4_t acc[4][4] = {};

    for (int kb = kb0; kb < kb1; ++kb) {
        const float* Bmat = B + zB + (long long)(bidx ? bidx[kb] : 0)*Bstr;
        const float* Abase;
        if (src) Abase = A + ((long long)s_srcf[r*KBtot + kb] << kbs_shift);
        else     Abase = A + zA + (long long)(row0 + r)*Ktot + ((long long)kb << kbs_shift);
        const float* Brow = Bmat + (long long)(col0 + r)*KBS;

        for (int kk = 0; kk < KBS; kk += 32) {
            // ---- stage: fp32 -> split bf16 hi/lo into LDS ----
            const float* ap = Abase + kk + half*16;
            const float* bp = Brow  + kk + half*16;
            float fa[16], fb[16];
            *(float4*)&fa[0]  = *(const float4*)(ap);
            *(float4*)&fa[4]  = *(const float4*)(ap+4);
            *(float4*)&fa[8]  = *(const float4*)(ap+8);
            *(float4*)&fa[12] = *(const float4*)(ap+12);
            *(float4*)&fb[0]  = *(const float4*)(bp);
            *(float4*)&fb[4]  = *(const float4*)(bp+4);
            *(float4*)&fb[8]  = *(const float4*)(bp+8);
            *(float4*)&fb[12] = *(const float4*)(bp+12);
            bf8_t ahv0, alv0, ahv1, alv1, bhv0, blv0, bhv1, blv1;
            #pragma unroll
            for (int j = 0; j < 8; ++j) {
                unsigned short h;
                h = f2bf(fa[j]);   ahv0[j] = (short)h; alv0[j] = (short)f2bf(fa[j]   - bf2f(h));
                h = f2bf(fa[j+8]); ahv1[j] = (short)h; alv1[j] = (short)f2bf(fa[j+8] - bf2f(h));
                h = f2bf(fb[j]);   bhv0[j] = (short)h; blv0[j] = (short)f2bf(fb[j]   - bf2f(h));
                h = f2bf(fb[j+8]); bhv1[j] = (short)h; blv1[j] = (short)f2bf(fb[j+8] - bf2f(h));
            }
            int co = half*16;
            *(bf8_t*)&Ah[r][co]   = ahv0;  *(bf8_t*)&Ah[r][co+8] = ahv1;
            *(bf8_t*)&Al[r][co]   = alv0;  *(bf8_t*)&Al[r][co+8] = alv1;
            *(bf8_t*)&Bh[r][co]   = bhv0;  *(bf8_t*)&Bh[r][co+8] = bhv1;
            *(bf8_t*)&Bl[r][co]   = blv0;  *(bf8_t*)&Bl[r][co+8] = blv1;
            __syncthreads();

            // ---- fragments + 3-segment MFMA ----
            bf8_t fah[4], fal[4], fbh[4], fbl[4];
            #pragma unroll
            for (int f = 0; f < 4; ++f) {
                fah[f] = *(const bf8_t*)&Ah[wr + f*16 + m16][q*8];
                fal[f] = *(const bf8_t*)&Al[wr + f*16 + m16][q*8];
                fbh[f] = *(const bf8_t*)&Bh[wc + f*16 + m16][q*8];
                fbl[f] = *(const bf8_t*)&Bl[wc + f*16 + m16][q*8];
            }
            #pragma unroll
            for (int fr = 0; fr < 4; ++fr)
                #pragma unroll
                for (int fc = 0; fc < 4; ++fc) {
                    acc[fr][fc] = __builtin_amdgcn_mfma_f32_16x16x32_bf16(fah[fr], fbh[fc], acc[fr][fc], 0, 0, 0);
                    acc[fr][fc] = __builtin_amdgcn_mfma_f32_16x16x32_bf16(fal[fr], fbh[fc], acc[fr][fc], 0, 0, 0);
                    acc[fr][fc] = __builtin_amdgcn_mfma_f32_16x16x32_bf16(fah[fr], fbl[fc], acc[fr][fc], 0, 0, 0);
                }
            __syncthreads();
        }
    }

    // ---- epilogue ----
    #pragma unroll
    for (int fr = 0; fr < 4; ++fr) {
        int gr0 = row0 + wr + fr*16 + q*4;
        #pragma unroll
        for (int fc = 0; fc < 4; ++fc) {
            int gc = col0 + wc + fc*16 + m16;
            f4_t v = acc[fr][fc];
            #pragma unroll
            for (int rr = 0; rr < 4; ++rr) {
                int R = gr0 + rr;
                if (R < M) {
                    float val = v[rr];
                    if (EPI == 1) val += bias[gc];
                    long long ci = zC + (long long)R*ldc + gc;
                    if (EPI == 2) atomicAdd(&C[ci], val);
                    else          C[ci] = val;
                }
            }
        }
    }
}

// ---------------- biasv[n] = sum_{k=0..15} (P_k (b_ih+b_hh))[n] -------------
__global__ void biasv_kernel(const float* __restrict__ P,
                             const float* __restrict__ b_ih,
                             const float* __restrict__ b_hh,
                             float* __restrict__ biasv)
{
    int n = blockIdx.x;
    float s = 0.f;
    for (int m = threadIdx.x; m < DH; m += 256) {
        float bb = b_ih[m] + b_hh[m];
        float ps = 0.f;
        #pragma unroll
        for (int k = 0; k < 16; ++k) ps += P[(long long)k*SZLL + (long long)n*DH + m];
        s += ps * bb;
    }
    __shared__ float red[256];
    red[threadIdx.x] = s; __syncthreads();
    for (int w = 128; w > 0; w >>= 1) {
        if (threadIdx.x < w) red[threadIdx.x] += red[threadIdx.x + w];
        __syncthreads();
    }
    if (threadIdx.x == 0) biasv[n] = red[0];
}

// ---------------- level-2 scan step: Hout = (b<nfull ? S16 Hin + W : Hin) ---
__global__ __launch_bounds__(256)
void step2_kernel(const float* __restrict__ Hin, const float* __restrict__ S16,
                  const float* __restrict__ Wg, float* __restrict__ Hout, int nfull)
{
    __shared__ float As[16][17];
    __shared__ float Bs[16][68];
    int tid = threadIdx.x;
    int tx = tid & 15, ty = tid >> 4;
    int r0 = blockIdx.x * 16;
    int col0 = blockIdx.y * 64;
    int bn = tid >> 2, bkq = tid & 3;
    float acc[4] = {0.f,0.f,0.f,0.f};
    for (int kt = 0; kt < DH; kt += 16) {
        As[tx][ty] = Hin[(long long)(r0+ty)*DH + kt + tx];
        float4 bv = *(const float4*)(S16 + (long long)(col0+bn)*DH + kt + bkq*4);
        Bs[bkq*4+0][bn]=bv.x; Bs[bkq*4+1][bn]=bv.y; Bs[bkq*4+2][bn]=bv.z; Bs[bkq*4+3][bn]=bv.w;
        __syncthreads();
        #pragma unroll
        for (int k = 0; k < 16; ++k) {
            float a = As[k][ty];
            float4 b4 = *(const float4*)&Bs[k][tx*4];
            acc[0] += a*b4.x; acc[1] += a*b4.y; acc[2] += a*b4.z; acc[3] += a*b4.w;
        }
        __syncthreads();
    }
    int row = r0 + ty;
    float4 ov;
    if (row < nfull) {
        const float* wr2 = Wg + (long long)row*DH + col0 + tx*4;
        ov.x = acc[0]+wr2[0]; ov.y = acc[1]+wr2[1]; ov.z = acc[2]+wr2[2]; ov.w = acc[3]+wr2[3];
    } else {
        ov = *(const float4*)(Hin + (long long)row*DH + col0 + tx*4);
    }
    *(float4*)(Hout + (long long)row*DH + col0 + tx*4) = ov;
}

// ---------------- output gather -------------------------------------------
__global__ void out_kernel(const float* __restrict__ H, const int* __restrict__ unsort32,
                           const int* __restrict__ flag, float* __restrict__ out)
{
    int i = blockIdx.x*blockDim.x + threadIdx.x;
    int qq = i >> 10, n = i & (DH-1);
    int shf = flag[0];
    out[i] = H[(long long)unsort32[qq << shf]*DH + n];
}

extern "C" void kernel_launch(void* const* d_in, const int* in_sizes, int n_in,
                              void* d_out, int out_size, void* d_ws, size_t ws_size,
                              hipStream_t stream)
{
    const float* data   = (const float*)d_in[0];
    const int*   bsz    = (const int*)d_in[1];
    const int*   unsort = (const int*)d_in[2];
    const float* W_ih   = (const float*)d_in[3];
    const float* b_ih   = (const float*)d_in[4];
    const float* W_hh   = (const float*)d_in[5];
    const float* b_hh   = (const float*)d_in[6];
    float* out = (float*)d_out;

    char* ws = (char*)d_ws;
    size_t off = 0;
    auto alloc = [&](size_t bytes) -> void* {
        void* p = ws + off;
        off = (off + bytes + 255) & ~(size_t)255;
        return p;
    };
    int*   pstart   = (int*)  alloc((NCHUNK+1)*4);
    int*   nbt      = (int*)  alloc(NCHUNK*4);
    int*   srcrow   = (int*)  alloc((size_t)NPAIR*CSZ*4);
    int*   wsrc     = (int*)  alloc((size_t)384*CSZ*4);
    int*   fix_src  = (int*)  alloc((size_t)64*17*4);
    int*   bidx_w   = (int*)  alloc(16*4);
    int*   bidx_fix = (int*)  alloc(17*4);
    int*   idt      = (int*)  alloc(17*4);
    int*   flag     = (int*)  alloc(4);
    float* P        = (float*)alloc(17ull*DH*DH*4);   // P_0..P_16 / S slots
    float* Tarr     = (float*)alloc(8ull*DH*DH*4);    // T slots 1..8 (transposes)
    float* WihT     = (float*)alloc((size_t)DIN*DH*4);
    float* Q        = (float*)alloc(16ull*DH*DIN*4);
    float* biasv    = (float*)alloc((size_t)DH*4);
    float* Vbig     = (float*)alloc((size_t)(NPAIR+576)*DH*4); // V | Hsnap | ZROW
    float* W        = (float*)alloc((size_t)384*DH*4);
    float* Hfinal   = (float*)alloc((size_t)BB*DH*4);
    (void)ws_size; (void)n_in; (void)in_sizes; (void)nbt;

    const size_t SZ = (size_t)DH*DH;
    auto sslot = [](int j){ return j == 0 ? 15 : (j == 1 ? 16 : j - 2); };

    setup_kernel<<<1,256,0,stream>>>(bsz, pstart, nbt, srcrow, wsrc, fix_src,
                                     bidx_w, bidx_fix, idt, flag);
    init_kernel<<<(DH*DH+255)/256,256,0,stream>>>(W_hh, P, Vbig, W, Hfinal);
    transpose_kernel<<<dim3(32,16,1),256,0,stream>>>(W_ih, WihT, 0, 0, DH, DIN);

    // ---- P-ladder: P_{m+j} = P_m * P_j via NT (B = T_j) ----
    transpose_kernel<<<dim3(32,32,1),256,0,stream>>>(P + SZ, Tarr, 0, 0, DH, DH);
    for (int m = 1; m <= 8; m <<= 1) {
        mfma_nt<0><<<dim3(8,8,m),256,0,stream>>>(
            P + (size_t)m*SZ, 0,
            Tarr, 0, (long long)SZ,
            P + (size_t)(m+1)*SZ, (long long)SZ, DH,
            nullptr, nullptr, nullptr,
            DH, 1, 10, 1);
        int lo = m+1, hi = 2*m < 8 ? 2*m : 8;   // transpose new P_j, j<=8
        if (hi >= lo) {
            int cnt = hi - lo + 1;
            transpose_kernel<<<dim3(32,32,cnt),256,0,stream>>>(
                P + (size_t)lo*SZ, Tarr + (size_t)(lo-1)*SZ,
                (long long)SZ, (long long)SZ, DH, DH);
        }
    }
    // ---- Q_j = P_{15-j} * W_ih  (z=16, NT with B = WihT) ----
    mfma_nt<0><<<dim3(8,4,16),256,0,stream>>>(
        P + 15ull*SZ, -(long long)SZ,
        WihT, 0, 0,
        Q, (long long)DH*DIN, DIN,
        nullptr, nullptr, nullptr,
        DH, 1, 10, 1);
    biasv_kernel<<<DH,256,0,stream>>>(P, b_ih, b_hh, biasv);

    // ---- V: gathered data x Q_j, + biasv ----
    mfma_nt<1><<<dim3((NPAIR+127)/128, 8, 1),256,0,stream>>>(
        data, 0,
        Q, (long long)DH*DIN, 0,
        Vbig, 0, DH,
        srcrow, idt, biasv,
        NPAIR, 16, 9, 16);

    // ---- S-ladder: S_j = P16^j, aliased into P slots ----
    initS_kernel<<<(DH*DH+255)/256,256,0,stream>>>(P);   // slot15 = I = S_0
    transpose_kernel<<<dim3(32,32,1),256,0,stream>>>(P + 16ull*SZ, Tarr, 0, 0, DH, DH);
    for (int m = 1; m <= 8; m <<= 1) {
        const float* Aop = P + (size_t)(m == 1 ? 16 : m - 2)*SZ;   // S_m
        mfma_nt<0><<<dim3(8,8,m),256,0,stream>>>(
            Aop, 0,
            Tarr, 0, (long long)SZ,
            P + (size_t)(m-1)*SZ, (long long)SZ, DH,   // slots sslot(m+1)..sslot(2m)
            nullptr, nullptr, nullptr,
            DH, 1, 10, 1);
        int lo = m+1, hi = 2*m < 8 ? 2*m : 8;   // transpose new S_j, j<=8
        if (hi >= lo) {
            int cnt = hi - lo + 1;
            transpose_kernel<<<dim3(32,32,cnt),256,0,stream>>>(
                P + (size_t)(lo-2)*SZ, Tarr + (size_t)(lo-1)*SZ,
                (long long)SZ, (long long)SZ, DH, DH);
        }
    }

    // ---- w_g gather-GEMM (split-K z=8, atomic into zeroed W) ----
    mfma_nt<2><<<dim3((NWP+127)/128, 8, 8),256,0,stream>>>(
        Vbig, 0,
        P, (long long)SZ, 0,
        W, 0, DH,
        wsrc, bidx_w, nullptr,
        NWP, 16, 10, 2);

    // ---- level-2 scan: 7 steps over group snapshots ----
    int wps = 0;
    for (int g = 0; g < 7; ++g) {
        int nf = 113 - 16*g; if (nf > 64) nf = 64;
        step2_kernel<<<dim3(4,16),256,0,stream>>>(
            Vbig + (size_t)(NPAIR + 64*g)*DH,
            P + (size_t)sslot(16)*SZ,
            W + (size_t)wps*DH,
            Vbig + (size_t)(NPAIR + 64*(g+1))*DH,
            nf);
        wps += nf;
    }

    // ---- finalize all 64 rows (split-K z=17, atomic into zeroed Hfinal) ----
    mfma_nt<2><<<dim3(1, 8, 17),256,0,stream>>>(
        Vbig, 0,
        P, (long long)SZ, 0,
        Hfinal, 0, DH,
        fix_src, bidx_fix, nullptr,
        BB, 17, 10, 1);

    out_kernel<<<out_size/256,256,0,stream>>>(Hfinal, unsort, flag, out);
}

// Round 4
// 1712.393 us; speedup vs baseline: 4.2191x; 1.1967x over previous
//
#include <hip/hip_runtime.h>

// LinearRNN: packed-sequence linear recurrence h' = W_hh h + W_ih x + b.
// Two-level chunking (exact) + closed-form level-2 scan:
//   v_c = sum_j Q_j x + biasv (Q_j = P_{15-j} W_ih), P_k = W_hh^k
//   w_g = sum_j S_{15-j} v_{16g+j}   (S_j = P16^j)
//   Hsnap[g] = sum_k T_k w_{g-1-k}   (T_k = S16^k)  -- no sequential scan
//   h_b = sum_{k<a_b} S_k v_{127-b-k} + S_{a_b} Hsnap[g_b]
// Heavy GEMMs: mfma_nt = split-bf16 x3 (fp32-accurate); V GEMM = dedicated
// 1-segment bf16 kernel (error ~2^-9 rel, well under threshold).

#define DH   1024
#define DIN  512
#define TT   2048
#define BB   64
#define NCHUNK 128
#define CSZ  16
#define NPAIR 6176         // sum_c nb[c]
#define NWP  355           // sum_{g=0..6} min(64,113-16g)
#define ZROW (NPAIR+512)   // zero row in Vbig
#define WZERO 383          // zero row in W array
#define SZLL 1048576ll     // DH*DH

typedef __attribute__((ext_vector_type(8))) short bf8_t;
typedef __attribute__((ext_vector_type(8))) unsigned short us8;
typedef __attribute__((ext_vector_type(4))) float f4_t;

__device__ __forceinline__ unsigned short f2bf(float x) {
    unsigned u = __float_as_uint(x);
    u += 0x7fffu + ((u >> 16) & 1u);
    return (unsigned short)(u >> 16);
}
__device__ __forceinline__ float bf2f(unsigned short h) {
    return __uint_as_float((unsigned)h << 16);
}
__device__ __forceinline__ int sslot_dev(int j) {
    return j == 0 ? 15 : (j == 1 ? 16 : j - 2);
}

// ---------------- setup: chunk / gather tables ------------------------------
__global__ void setup_kernel(const int* __restrict__ bsz32,
                             int* __restrict__ srcrow,
                             int* __restrict__ wsrc, int* __restrict__ fix_src,
                             int* __restrict__ snap_src,
                             int* __restrict__ bidx_w, int* __restrict__ bidx_fix,
                             int* __restrict__ bidx_snap, int* __restrict__ flag)
{
    __shared__ int sbs[TT];
    __shared__ int soff[TT];
    __shared__ int snb[NCHUNK];
    __shared__ int sps[NCHUNK];
    __shared__ int s_nf[7], s_wps[7];
    __shared__ int sh_shift;
    int tid = threadIdx.x;
    if (tid == 0) {
        sh_shift = (bsz32[1] == 0) ? 1 : 0;   // int64 detection
        flag[0] = sh_shift;
    }
    __syncthreads();
    int shf = sh_shift;
    for (int t = tid; t < TT; t += 256) sbs[t] = bsz32[t << shf];
    __syncthreads();
    if (tid == 0) {
        int run = 0;
        for (int t = 0; t < TT; ++t) { soff[t] = run; run += sbs[t]; }
        int pr = 0;
        for (int c = 0; c < NCHUNK; ++c) { snb[c] = sbs[c*CSZ]; sps[c] = pr; pr += snb[c]; }
        int wp = 0;
        for (int g = 0; g < 7; ++g) {
            int nf = 113 - 16*g; if (nf > 64) nf = 64;
            s_nf[g] = nf; s_wps[g] = wp; wp += nf;
        }
    }
    __syncthreads();
    // srcrow for V gather
    for (int c = 0; c < NCHUNK; ++c) {
        int n = snb[c], ps = sps[c];
        for (int b = tid; b < n; b += 256) {
            #pragma unroll
            for (int j = 0; j < CSZ; ++j)
                srcrow[(ps + b)*CSZ + j] = soff[c*CSZ + j] + b;
        }
    }
    // wsrc for w gather-GEMM
    for (int g = 0; g < 7; ++g) {
        for (int b = tid; b < s_nf[g]; b += 256) {
            int wp = s_wps[g] + b;
            #pragma unroll
            for (int j = 0; j < CSZ; ++j)
                wsrc[wp*CSZ + j] = sps[16*g + j] + b;
        }
    }
    // fix_src: row b, 17 blocks
    if (tid < 64) {
        int b = tid;
        int gb = (127 - b) >> 4;
        int ab = 16 - (b & 15);
        for (int k = 0; k <= 16; ++k) {
            int r;
            if (k < ab)       r = sps[127 - b - k] + b;
            else if (k == ab) r = NPAIR + 64*gb + b;
            else              r = ZROW;
            fix_src[b*17 + k] = r;
        }
    }
    // snap_src: snapshots g=4..7, p = 64*(g-4)+b, 7 K-blocks
    if (tid < 256) {
        int g = 4 + (tid >> 6), b = tid & 63;
        for (int k = 0; k < 7; ++k) {
            int j = g - 1 - k;
            int rsrc = (j >= 0 && j <= 6 && b < s_nf[j]) ? (s_wps[j] + b) : WZERO;
            snap_src[tid*7 + k] = rsrc;
        }
    }
    if (tid < 16) bidx_w[tid]    = sslot_dev(15 - tid);
    if (tid < 17) bidx_fix[tid]  = sslot_dev(tid);
    if (tid < 7)  bidx_snap[tid] = (tid == 0) ? 15 : (tid == 1 ? 14 : 15 + tid);
}

// ---------------- init: P0 = I, P1 = W_hh, zero Vbig tail / W / Hfinal ------
__global__ void init_kernel(const float* __restrict__ W_hh,
                            float* __restrict__ P, float* __restrict__ Vbig,
                            float* __restrict__ W, float* __restrict__ Hf)
{
    long long i = (long long)blockIdx.x*blockDim.x + threadIdx.x;
    if (i < SZLL) {
        int r = (int)(i >> 10), cc = (int)(i & 1023);
        P[i] = (r == cc) ? 1.0f : 0.0f;
        P[SZLL + i] = W_hh[i];
    }
    if (i < 576ll*DH) Vbig[(long long)NPAIR*DH + i] = 0.0f;
    if (i < 384ll*DH) W[i] = 0.0f;
    if (i < 64ll*DH)  Hf[i] = 0.0f;
}

// ---------------- identity into P slot 15 (S_0), after Q/biasv read P_15 ----
__global__ void initS_kernel(float* __restrict__ P)
{
    long long i = (long long)blockIdx.x*blockDim.x + threadIdx.x;
    if (i < SZLL) {
        int r = (int)(i >> 10), cc = (int)(i & 1023);
        P[15*SZLL + i] = (r == cc) ? 1.0f : 0.0f;
    }
}

// ---------------- helpers ---------------------------------------------------
__global__ void zero_kernel(float* __restrict__ p, long long n4)
{
    for (long long i = (long long)blockIdx.x*blockDim.x + threadIdx.x; i < n4;
         i += (long long)gridDim.x*blockDim.x)
        *(float4*)(p + i*4) = make_float4(0.f,0.f,0.f,0.f);
}

__global__ void fillV_kernel(float* __restrict__ V, const float* __restrict__ biasv)
{
    for (long long i = (long long)blockIdx.x*blockDim.x + threadIdx.x;
         i < (long long)NPAIR*256; i += (long long)gridDim.x*blockDim.x) {
        int col = (int)(i & 255) << 2;
        *(float4*)(V + i*4) = *(const float4*)(biasv + col);
    }
}

__global__ void convertQ_kernel(const float* __restrict__ Q, unsigned short* __restrict__ Qh)
{
    long long i = ((long long)blockIdx.x*blockDim.x + threadIdx.x) * 8;
    float4 a = *(const float4*)(Q + i);
    float4 b = *(const float4*)(Q + i + 4);
    us8 v;
    v[0]=f2bf(a.x); v[1]=f2bf(a.y); v[2]=f2bf(a.z); v[3]=f2bf(a.w);
    v[4]=f2bf(b.x); v[5]=f2bf(b.y); v[6]=f2bf(b.z); v[7]=f2bf(b.w);
    *(us8*)(Qh + i) = v;
}

// ---------------- generic fp32 transpose: dst = src^T (z-batched) -----------
__global__ void transpose_kernel(const float* __restrict__ src, float* __restrict__ dst,
                                 long long sstr, long long dstr, int R, int C)
{
    __shared__ float tile[32][33];
    const float* S = src + sstr*blockIdx.z;
    float* D = dst + dstr*blockIdx.z;
    int r0 = blockIdx.x*32, c0 = blockIdx.y*32;
    int tx = threadIdx.x & 31, ty = threadIdx.x >> 5;
    #pragma unroll
    for (int i = 0; i < 4; ++i)
        tile[ty + i*8][tx] = S[(long long)(r0 + ty + i*8)*C + c0 + tx];
    __syncthreads();
    #pragma unroll
    for (int i = 0; i < 4; ++i)
        D[(long long)(c0 + ty + i*8)*R + r0 + tx] = tile[tx][ty + i*8];
}

// ---------------- universal split-bf16 (x3) MFMA NT GEMM --------------------
// C[r][c] (+)= sum_kb sum_kk A(r,kb,kk) * B'(kb)[c][kk]
//   z = batch*nsplit + ks; kb range = [ks*KBtot/nsplit, ...+KBtot/nsplit)
//   A: gather (src rows, unit KBS) or dense (row len Ktot, batch stride Astr)
//   B: bidx slab mode (row len KBS) or dense (row len Ktot, batch stride Bzstr)
// EPI: 0 = store, 2 = atomicAdd (required when nsplit>1).
template<int EPI>
__global__ __launch_bounds__(256)
void mfma_nt(const float* __restrict__ A, long long Astr,
             const float* __restrict__ B, long long Bstr, long long Bzstr,
             float* __restrict__ C, long long Cstr, int ldc,
             const int* __restrict__ src, const int* __restrict__ bidx,
             int M, int KBtot, int kbs_shift, int nsplit)
{
    __shared__ __align__(16) short Ah[128][40];
    __shared__ __align__(16) short Al[128][40];
    __shared__ __align__(16) short Bh[128][40];
    __shared__ __align__(16) short Bl[128][40];
    __shared__ int s_srcf[128*17];

    int tid = threadIdx.x;
    int row0 = blockIdx.x * 128;
    int col0 = blockIdx.y * 128;
    int z = blockIdx.z;
    int batch = z / nsplit;
    int ks = z - batch*nsplit;
    int kbspan = KBtot / nsplit;
    int kb0 = ks*kbspan, kb1 = kb0 + kbspan;
    int KBS = 1 << kbs_shift;
    int Ktot = KBtot << kbs_shift;
    long long zA = Astr*batch, zB = Bzstr*batch, zC = Cstr*batch;

    if (src) {
        for (int i = tid; i < 128*KBtot; i += 256) {
            int r = i / KBtot, kb = i - r*KBtot;
            int p = row0 + r; if (p > M-1) p = M-1;
            s_srcf[i] = src[p*KBtot + kb];
        }
        __syncthreads();
    }

    int r = tid >> 1, half = tid & 1;
    int lane = tid & 63, wv = tid >> 6;
    int wr = (wv & 1) * 64, wc = (wv >> 1) * 64;
    int m16 = lane & 15, q = lane >> 4;

    f4_t acc[4][4] = {};

    for (int kb = kb0; kb < kb1; ++kb) {
        const float* Bmat = B + zB + (bidx ? (long long)bidx[kb]*Bstr : 0ll);
        const float* Abase;
        if (src) Abase = A + ((long long)s_srcf[r*KBtot + kb] << kbs_shift);
        else     Abase = A + zA + (long long)(row0 + r)*Ktot + ((long long)kb << kbs_shift);
        const float* Brow;
        if (bidx) Brow = Bmat + (long long)(col0 + r)*KBS;
        else      Brow = Bmat + (long long)(col0 + r)*Ktot + ((long long)kb << kbs_shift);

        for (int kk = 0; kk < KBS; kk += 32) {
            const float* ap = Abase + kk + half*16;
            const float* bp = Brow  + kk + half*16;
            float fa[16], fb[16];
            *(float4*)&fa[0]  = *(const float4*)(ap);
            *(float4*)&fa[4]  = *(const float4*)(ap+4);
            *(float4*)&fa[8]  = *(const float4*)(ap+8);
            *(float4*)&fa[12] = *(const float4*)(ap+12);
            *(float4*)&fb[0]  = *(const float4*)(bp);
            *(float4*)&fb[4]  = *(const float4*)(bp+4);
            *(float4*)&fb[8]  = *(const float4*)(bp+8);
            *(float4*)&fb[12] = *(const float4*)(bp+12);
            bf8_t ahv0, alv0, ahv1, alv1, bhv0, blv0, bhv1, blv1;
            #pragma unroll
            for (int j = 0; j < 8; ++j) {
                unsigned short h;
                h = f2bf(fa[j]);   ahv0[j] = (short)h; alv0[j] = (short)f2bf(fa[j]   - bf2f(h));
                h = f2bf(fa[j+8]); ahv1[j] = (short)h; alv1[j] = (short)f2bf(fa[j+8] - bf2f(h));
                h = f2bf(fb[j]);   bhv0[j] = (short)h; blv0[j] = (short)f2bf(fb[j]   - bf2f(h));
                h = f2bf(fb[j+8]); bhv1[j] = (short)h; blv1[j] = (short)f2bf(fb[j+8] - bf2f(h));
            }
            int co = half*16;
            *(bf8_t*)&Ah[r][co]   = ahv0;  *(bf8_t*)&Ah[r][co+8] = ahv1;
            *(bf8_t*)&Al[r][co]   = alv0;  *(bf8_t*)&Al[r][co+8] = alv1;
            *(bf8_t*)&Bh[r][co]   = bhv0;  *(bf8_t*)&Bh[r][co+8] = bhv1;
            *(bf8_t*)&Bl[r][co]   = blv0;  *(bf8_t*)&Bl[r][co+8] = blv1;
            __syncthreads();

            bf8_t fah[4], fal[4], fbh[4], fbl[4];
            #pragma unroll
            for (int f = 0; f < 4; ++f) {
                fah[f] = *(const bf8_t*)&Ah[wr + f*16 + m16][q*8];
                fal[f] = *(const bf8_t*)&Al[wr + f*16 + m16][q*8];
                fbh[f] = *(const bf8_t*)&Bh[wc + f*16 + m16][q*8];
                fbl[f] = *(const bf8_t*)&Bl[wc + f*16 + m16][q*8];
            }
            #pragma unroll
            for (int fr = 0; fr < 4; ++fr)
                #pragma unroll
                for (int fc = 0; fc < 4; ++fc) {
                    acc[fr][fc] = __builtin_amdgcn_mfma_f32_16x16x32_bf16(fah[fr], fbh[fc], acc[fr][fc], 0, 0, 0);
                    acc[fr][fc] = __builtin_amdgcn_mfma_f32_16x16x32_bf16(fal[fr], fbh[fc], acc[fr][fc], 0, 0, 0);
                    acc[fr][fc] = __builtin_amdgcn_mfma_f32_16x16x32_bf16(fah[fr], fbl[fc], acc[fr][fc], 0, 0, 0);
                }
            __syncthreads();
        }
    }

    #pragma unroll
    for (int fr = 0; fr < 4; ++fr) {
        int gr0 = row0 + wr + fr*16 + q*4;
        #pragma unroll
        for (int fc = 0; fc < 4; ++fc) {
            int gc = col0 + wc + fc*16 + m16;
            f4_t v = acc[fr][fc];
            #pragma unroll
            for (int rr = 0; rr < 4; ++rr) {
                int R = gr0 + rr;
                if (R < M) {
                    long long ci = zC + (long long)R*ldc + gc;
                    if (EPI == 2) atomicAdd(&C[ci], v[rr]);
                    else          C[ci] = v[rr];
                }
            }
        }
    }
}

// ---------------- dedicated V GEMM: 1-segment bf16, gathered A --------------
// V[p,n] += sum_j data[srcrow[p][j]] . Qh_j[n]   (z = K-half, atomic epilogue)
__global__ __launch_bounds__(256, 3)
void vgemm_kernel(const float* __restrict__ data, const unsigned short* __restrict__ Qh,
                  const int* __restrict__ srcrow, float* __restrict__ V)
{
    __shared__ __align__(16) unsigned short Ah[128][72];
    __shared__ __align__(16) unsigned short Bh[128][72];
    int tid = threadIdx.x;
    int p0 = blockIdx.x * 128, col0 = blockIdx.y * 128;
    int z = blockIdx.z;
    int r = tid >> 1, half = tid & 1;
    int pA = p0 + r; if (pA > NPAIR-1) pA = NPAIR-1;
    const int* srow = srcrow + pA*CSZ;

    int lane = tid & 63, wv = tid >> 6;
    int wr = (wv & 1) * 64, wc = (wv >> 1) * 64;
    int m16 = lane & 15, q = lane >> 4;

    f4_t acc[4][4] = {};

    for (int kt = 0; kt < 64; ++kt) {
        int kb = z*8 + (kt >> 3);
        int koff = (kt & 7)*64 + half*32;
        // A: fp32 data -> bf16 hi
        const float* ap = data + (long long)srow[kb]*DIN + koff;
        float fa[32];
        #pragma unroll
        for (int i = 0; i < 8; ++i) *(float4*)&fa[i*4] = *(const float4*)(ap + i*4);
        // B: preconverted bf16
        const unsigned short* bp = Qh + ((long long)(kb*DH + col0 + r))*DIN + koff;
        uint4 b0 = *(const uint4*)(bp);
        uint4 b1 = *(const uint4*)(bp + 8);
        uint4 b2 = *(const uint4*)(bp + 16);
        uint4 b3 = *(const uint4*)(bp + 24);
        us8 va0, va1, va2, va3;
        #pragma unroll
        for (int i = 0; i < 8; ++i) {
            va0[i] = f2bf(fa[i]);      va1[i] = f2bf(fa[8+i]);
            va2[i] = f2bf(fa[16+i]);   va3[i] = f2bf(fa[24+i]);
        }
        int ac = half*32;
        *(us8*)&Ah[r][ac]      = va0;  *(us8*)&Ah[r][ac+8]  = va1;
        *(us8*)&Ah[r][ac+16]   = va2;  *(us8*)&Ah[r][ac+24] = va3;
        *(uint4*)&Bh[r][ac]    = b0;   *(uint4*)&Bh[r][ac+8]  = b1;
        *(uint4*)&Bh[r][ac+16] = b2;   *(uint4*)&Bh[r][ac+24] = b3;
        __syncthreads();

        #pragma unroll
        for (int ks = 0; ks < 2; ++ks) {
            bf8_t fa4[4], fb4[4];
            #pragma unroll
            for (int f = 0; f < 4; ++f) {
                fa4[f] = *(const bf8_t*)&Ah[wr + f*16 + m16][ks*32 + q*8];
                fb4[f] = *(const bf8_t*)&Bh[wc + f*16 + m16][ks*32 + q*8];
            }
            #pragma unroll
            for (int fr = 0; fr < 4; ++fr)
                #pragma unroll
                for (int fc = 0; fc < 4; ++fc)
                    acc[fr][fc] = __builtin_amdgcn_mfma_f32_16x16x32_bf16(fa4[fr], fb4[fc], acc[fr][fc], 0, 0, 0);
        }
        __syncthreads();
    }

    #pragma unroll
    for (int fr = 0; fr < 4; ++fr) {
        int gr0 = p0 + wr + fr*16 + q*4;
        #pragma unroll
        for (int fc = 0; fc < 4; ++fc) {
            int gc = col0 + wc + fc*16 + m16;
            f4_t v = acc[fr][fc];
            #pragma unroll
            for (int rr = 0; rr < 4; ++rr) {
                int p = gr0 + rr;
                if (p < NPAIR) atomicAdd(&V[(long long)p*DH + gc], v[rr]);
            }
        }
    }
}

// ---------------- biasv[n] = sum_{k=0..15} (P_k (b_ih+b_hh))[n] -------------
__global__ void biasv_kernel(const float* __restrict__ P,
                             const float* __restrict__ b_ih,
                             const float* __restrict__ b_hh,
                             float* __restrict__ biasv)
{
    int n = blockIdx.x;
    float s = 0.f;
    for (int m = threadIdx.x; m < DH; m += 256) {
        float bb = b_ih[m] + b_hh[m];
        float ps = 0.f;
        #pragma unroll
        for (int k = 0; k < 16; ++k) ps += P[(long long)k*SZLL + (long long)n*DH + m];
        s += ps * bb;
    }
    __shared__ float red[256];
    red[threadIdx.x] = s; __syncthreads();
    for (int w = 128; w > 0; w >>= 1) {
        if (threadIdx.x < w) red[threadIdx.x] += red[threadIdx.x + w];
        __syncthreads();
    }
    if (threadIdx.x == 0) biasv[n] = red[0];
}

// ---------------- output gather -------------------------------------------
__global__ void out_kernel(const float* __restrict__ H, const int* __restrict__ unsort32,
                           const int* __restrict__ flag, float* __restrict__ out)
{
    int i = blockIdx.x*blockDim.x + threadIdx.x;
    int qq = i >> 10, n = i & (DH-1);
    int shf = flag[0];
    out[i] = H[(long long)unsort32[qq << shf]*DH + n];
}

extern "C" void kernel_launch(void* const* d_in, const int* in_sizes, int n_in,
                              void* d_out, int out_size, void* d_ws, size_t ws_size,
                              hipStream_t stream)
{
    const float* data   = (const float*)d_in[0];
    const int*   bsz    = (const int*)d_in[1];
    const int*   unsort = (const int*)d_in[2];
    const float* W_ih   = (const float*)d_in[3];
    const float* b_ih   = (const float*)d_in[4];
    const float* W_hh   = (const float*)d_in[5];
    const float* b_hh   = (const float*)d_in[6];
    float* out = (float*)d_out;

    char* ws = (char*)d_ws;
    size_t off = 0;
    auto alloc = [&](size_t bytes) -> void* {
        void* p = ws + off;
        off = (off + bytes + 255) & ~(size_t)255;
        return p;
    };
    int*   srcrow    = (int*)  alloc((size_t)NPAIR*CSZ*4);
    int*   wsrc      = (int*)  alloc((size_t)384*CSZ*4);
    int*   fix_src   = (int*)  alloc((size_t)64*17*4);
    int*   snap_src  = (int*)  alloc((size_t)256*7*4);
    int*   bidx_w    = (int*)  alloc(16*4);
    int*   bidx_fix  = (int*)  alloc(17*4);
    int*   bidx_snap = (int*)  alloc(7*4);
    int*   flag      = (int*)  alloc(4);
    float* P         = (float*)alloc(22ull*DH*DH*4);   // S_0..S_16 slots + T2..T6 (17..21)
    float* Tarr      = (float*)alloc(8ull*DH*DH*4);    // transposed B-operands
    float* WihT      = (float*)alloc((size_t)DIN*DH*4);
    float* Q         = (float*)alloc(16ull*DH*DIN*4);
    unsigned short* Qh = (unsigned short*)alloc(16ull*DH*DIN*2);
    float* biasv     = (float*)alloc((size_t)DH*4);
    float* Vbig      = (float*)alloc((size_t)(NPAIR+576)*DH*4); // V | Hsnap | ZROW
    float* W         = (float*)alloc((size_t)384*DH*4);
    float* Hfinal    = (float*)alloc((size_t)BB*DH*4);
    (void)ws_size; (void)n_in; (void)in_sizes;

    const size_t SZ = (size_t)DH*DH;

    setup_kernel<<<1,256,0,stream>>>(bsz, srcrow, wsrc, fix_src, snap_src,
                                     bidx_w, bidx_fix, bidx_snap, flag);
    init_kernel<<<(DH*DH+255)/256,256,0,stream>>>(W_hh, P, Vbig, W, Hfinal);
    transpose_kernel<<<dim3(32,16,1),256,0,stream>>>(W_ih, WihT, 0, 0, DH, DIN);
    transpose_kernel<<<dim3(32,32,1),256,0,stream>>>(P + SZ, Tarr, 0, 0, DH, DH);

    // ---- P-ladder: P_{m+j} = P_m * P_j (B' = P_j^T in Tarr) ----
    // m=1 (split-K x4, atomic):
    zero_kernel<<<1024,256,0,stream>>>(P + 2*SZ, SZLL/4);
    mfma_nt<2><<<dim3(8,8,4),256,0,stream>>>(P + SZ, 0, Tarr, 0, (long long)SZ,
        P + 2*SZ, (long long)SZ, DH, nullptr, nullptr, DH, 4, 8, 4);
    transpose_kernel<<<dim3(32,32,1),256,0,stream>>>(P + 2*SZ, Tarr + SZ, 0, 0, DH, DH);
    // m=2 (batch2 x split2):
    zero_kernel<<<1024,256,0,stream>>>(P + 3*SZ, 2*SZLL/4);
    mfma_nt<2><<<dim3(8,8,4),256,0,stream>>>(P + 2*SZ, 0, Tarr, 0, (long long)SZ,
        P + 3*SZ, (long long)SZ, DH, nullptr, nullptr, DH, 4, 8, 2);
    transpose_kernel<<<dim3(32,32,2),256,0,stream>>>(P + 3*SZ, Tarr + 2*SZ,
        (long long)SZ, (long long)SZ, DH, DH);
    // m=4 (batch4, store):
    mfma_nt<0><<<dim3(8,8,4),256,0,stream>>>(P + 4*SZ, 0, Tarr, 0, (long long)SZ,
        P + 5*SZ, (long long)SZ, DH, nullptr, nullptr, DH, 4, 8, 1);
    transpose_kernel<<<dim3(32,32,4),256,0,stream>>>(P + 5*SZ, Tarr + 4*SZ,
        (long long)SZ, (long long)SZ, DH, DH);
    // m=8 (batch8, store): P9..P16
    mfma_nt<0><<<dim3(8,8,8),256,0,stream>>>(P + 8*SZ, 0, Tarr, 0, (long long)SZ,
        P + 9*SZ, (long long)SZ, DH, nullptr, nullptr, DH, 4, 8, 1);

    // ---- Q_j = P_{15-j} * W_ih (batch16 x split2, atomic) ----
    zero_kernel<<<1024,256,0,stream>>>(Q, 16ll*DH*DIN/4);
    mfma_nt<2><<<dim3(8,4,32),256,0,stream>>>(P + 15*SZ, -(long long)SZ, WihT, 0, 0,
        Q, (long long)DH*DIN, DIN, nullptr, nullptr, DH, 4, 8, 2);
    biasv_kernel<<<DH,256,0,stream>>>(P, b_ih, b_hh, biasv);

    // ---- V: fill bias, convert Q to bf16, 1-seg bf16 gather GEMM ----
    fillV_kernel<<<2048,256,0,stream>>>(Vbig, biasv);
    convertQ_kernel<<<4096,256,0,stream>>>(Q, Qh);
    vgemm_kernel<<<dim3(49,8,2),256,0,stream>>>(data, Qh, srcrow, Vbig);

    // ---- S-ladder: S_j = P16^j in slots sslot(j) ----
    initS_kernel<<<(DH*DH+255)/256,256,0,stream>>>(P);   // slot15 = I = S_0
    transpose_kernel<<<dim3(32,32,1),256,0,stream>>>(P + 16*SZ, Tarr, 0, 0, DH, DH);
    // m=1: S2 -> slot0
    zero_kernel<<<1024,256,0,stream>>>(P, SZLL/4);
    mfma_nt<2><<<dim3(8,8,4),256,0,stream>>>(P + 16*SZ, 0, Tarr, 0, (long long)SZ,
        P, (long long)SZ, DH, nullptr, nullptr, DH, 4, 8, 4);
    transpose_kernel<<<dim3(32,32,1),256,0,stream>>>(P, Tarr + SZ, 0, 0, DH, DH);
    // m=2: S3,S4 -> slots 1,2
    zero_kernel<<<1024,256,0,stream>>>(P + SZ, 2*SZLL/4);
    mfma_nt<2><<<dim3(8,8,4),256,0,stream>>>(P, 0, Tarr, 0, (long long)SZ,
        P + SZ, (long long)SZ, DH, nullptr, nullptr, DH, 4, 8, 2);
    transpose_kernel<<<dim3(32,32,2),256,0,stream>>>(P + SZ, Tarr + 2*SZ,
        (long long)SZ, (long long)SZ, DH, DH);
    // m=4: S5..S8 -> slots 3..6
    mfma_nt<0><<<dim3(8,8,4),256,0,stream>>>(P + 2*SZ, 0, Tarr, 0, (long long)SZ,
        P + 3*SZ, (long long)SZ, DH, nullptr, nullptr, DH, 4, 8, 1);
    transpose_kernel<<<dim3(32,32,4),256,0,stream>>>(P + 3*SZ, Tarr + 4*SZ,
        (long long)SZ, (long long)SZ, DH, DH);
    // m=8: S9..S16 -> slots 7..14
    mfma_nt<0><<<dim3(8,8,8),256,0,stream>>>(P + 6*SZ, 0, Tarr, 0, (long long)SZ,
        P + 7*SZ, (long long)SZ, DH, nullptr, nullptr, DH, 4, 8, 1);

    // ---- T-ladder: T_k = S16^k, slots 17..21 (k=2..6) ----
    transpose_kernel<<<dim3(32,32,1),256,0,stream>>>(P + 14*SZ, Tarr, 0, 0, DH, DH); // S16^T
    zero_kernel<<<1024,256,0,stream>>>(P + 17*SZ, SZLL/4);
    mfma_nt<2><<<dim3(8,8,4),256,0,stream>>>(P + 14*SZ, 0, Tarr, 0, (long long)SZ,
        P + 17*SZ, (long long)SZ, DH, nullptr, nullptr, DH, 4, 8, 4);          // T2
    transpose_kernel<<<dim3(32,32,1),256,0,stream>>>(P + 17*SZ, Tarr + SZ, 0, 0, DH, DH); // T2^T
    zero_kernel<<<1024,256,0,stream>>>(P + 18*SZ, 2*SZLL/4);
    mfma_nt<2><<<dim3(8,8,4),256,0,stream>>>(P + 17*SZ, 0, Tarr, 0, (long long)SZ,
        P + 18*SZ, (long long)SZ, DH, nullptr, nullptr, DH, 4, 8, 2);          // T3, T4
    zero_kernel<<<1024,256,0,stream>>>(P + 20*SZ, 2*SZLL/4);
    mfma_nt<2><<<dim3(8,8,4),256,0,stream>>>(P + 19*SZ, 0, Tarr, 0, (long long)SZ,
        P + 20*SZ, (long long)SZ, DH, nullptr, nullptr, DH, 4, 8, 2);          // T5, T6

    // ---- w_g gather-GEMM (split-K x16, atomic into zeroed W) ----
    mfma_nt<2><<<dim3(3,8,16),256,0,stream>>>(Vbig, 0, P, (long long)SZ, 0,
        W, 0, DH, wsrc, bidx_w, NWP, 16, 10, 16);

    // ---- snapshots g=4..7: Hsnap[g] = sum_k T_k w_{g-1-k} (atomic, zeroed) --
    mfma_nt<2><<<dim3(2,8,7),256,0,stream>>>(W, 0, P, (long long)SZ, 0,
        Vbig + (size_t)(NPAIR+256)*DH, 0, DH, snap_src, bidx_snap, 256, 7, 10, 7);

    // ---- finalize all 64 rows (split-K x17, atomic into zeroed Hfinal) ----
    mfma_nt<2><<<dim3(1,8,17),256,0,stream>>>(Vbig, 0, P, (long long)SZ, 0,
        Hfinal, 0, DH, fix_src, bidx_fix, BB, 17, 10, 17);

    out_kernel<<<out_size/256,256,0,stream>>>(Hfinal, unsort, flag, out);
}